// Round 9
// baseline (464.879 us; speedup 1.0000x reference)
//
#include <hip/hip_runtime.h>
#include <hip/hip_bf16.h>
#include <math.h>

#define IN_DIM 512
#define HID    1024
#define NE     16
#define T_TOK  8192
#define NPAIR  (T_TOK*2)

typedef __attribute__((ext_vector_type(8))) short bf16x8;
typedef __attribute__((ext_vector_type(4))) float f32x4;

__device__ __forceinline__ unsigned short f2b(float f){
  unsigned u = __float_as_uint(f);
  u += 0x7FFF + ((u >> 16) & 1);           // round-to-nearest-even
  return (unsigned short)(u >> 16);
}
__device__ __forceinline__ float b2f(unsigned short u){
  return __uint_as_float(((unsigned)u) << 16);
}

// Barrier WITHOUT the vmcnt(0) drain __syncthreads() forces: wait only LDS ops,
// leave global prefetch loads in flight (AITER/m139 pattern).
__device__ __forceinline__ void barrier_lds_only(){
  asm volatile("s_waitcnt lgkmcnt(0)" ::: "memory");
  __builtin_amdgcn_s_barrier();
}

// ---------------- prep: batched transpose + convert: [B][M][N] f32 -> [B][N][M] bf16 ----
__global__ __launch_bounds__(256) void tconv_kernel(const float* __restrict__ in,
                                                    unsigned short* __restrict__ out,
                                                    int M, int N){
  __shared__ float tile[32][33];
  int e  = blockIdx.z;
  int m0 = blockIdx.y*32, n0 = blockIdx.x*32;
  const float* src = in + (size_t)e*M*N;
  unsigned short* dst = out + (size_t)e*M*N;
  int c = threadIdx.x & 31, r = threadIdx.x >> 5;   // 8 rows x 32 cols per pass
  #pragma unroll
  for (int i=0;i<4;i++)
    tile[r + i*8][c] = src[(size_t)(m0 + r + i*8)*N + n0 + c];
  __syncthreads();
  int tr  = threadIdx.x >> 3;          // 0..31 (dst row within tile)
  int tc4 = (threadIdx.x & 7) * 4;     // 0,4,...,28
  ushort4 o;
  o.x = f2b(tile[tc4+0][tr]); o.y = f2b(tile[tc4+1][tr]);
  o.z = f2b(tile[tc4+2][tr]); o.w = f2b(tile[tc4+3][tr]);
  *(ushort4*)(&dst[(size_t)(n0 + tr)*M + m0 + tc4]) = o;
}

// ---------------- router: one wave per token; NO global atomics, NO residual write ----
__global__ __launch_bounds__(256) void router_kernel(
    const float* __restrict__ x, const float* __restrict__ Wr, const float* __restrict__ br,
    unsigned short* __restrict__ xb, int* __restrict__ eid, float* __restrict__ pw)
{
  int wid = threadIdx.x >> 6, lane = threadIdx.x & 63;
  int t = blockIdx.x*4 + wid;
  const float4* xr4 = (const float4*)(x + (size_t)t*IN_DIM);
  ushort4*      xb4 = (ushort4*)(xb + (size_t)t*IN_DIM);

  float acc[NE];
  #pragma unroll
  for (int i=0;i<NE;i++) acc[i]=0.f;

  #pragma unroll
  for (int j=0;j<2;j++){
    int f = j*64 + lane;
    float4 v = xr4[f];
    ushort4 o; o.x=f2b(v.x); o.y=f2b(v.y); o.z=f2b(v.z); o.w=f2b(v.w);
    xb4[f] = o;
    const float4* wr4 = (const float4*)(Wr + (size_t)(f*4)*NE);
    const float* vv = (const float*)&v;
    #pragma unroll
    for (int rr=0; rr<4; rr++){
      float xv = vv[rr];
      #pragma unroll
      for (int q=0;q<4;q++){
        float4 w = wr4[rr*4+q];
        acc[q*4+0] += xv*w.x; acc[q*4+1] += xv*w.y;
        acc[q*4+2] += xv*w.z; acc[q*4+3] += xv*w.w;
      }
    }
  }
  #pragma unroll
  for (int off=32; off>=1; off>>=1){
    #pragma unroll
    for (int i=0;i<NE;i++) acc[i] += __shfl_xor(acc[i], off, 64);
  }
  if (lane==0){
    #pragma unroll
    for (int i=0;i<NE;i++) acc[i] += br[i];
    int e0=0; float l0=acc[0];
    #pragma unroll
    for (int i=1;i<NE;i++) if (acc[i] > l0){ l0=acc[i]; e0=i; }
    int e1=-1; float l1=-3.0e38f;
    #pragma unroll
    for (int i=0;i<NE;i++) if (i!=e0 && acc[i] > l1){ l1=acc[i]; e1=i; }
    float w0 = 1.f/(1.f + __expf(l1 - l0));
    float w1 = 1.f - w0;
    pw[t*2+0] = w0; pw[t*2+1] = w1;
    eid[t*2+0] = e0; eid[t*2+1] = e1;
  }
}

// ---------------- bucket build: 16 blocks (one per expert), ballot-compact ----------
__global__ __launch_bounds__(1024) void bucket_kernel(const int* __restrict__ eid,
                                                      int* __restrict__ cnt,
                                                      int* __restrict__ bucket){
  int e = blockIdx.x;
  __shared__ int lbase;
  if (threadIdx.x == 0) lbase = 0;
  __syncthreads();
  int lane = threadIdx.x & 63, wid = threadIdx.x >> 6;
  int* be = bucket + e*T_TOK;
  for (int c = wid*64; c < NPAIR; c += 1024){
    int p = c + lane;
    bool ok = (eid[p] == e);
    unsigned long long m = __ballot(ok);
    int rank = __popcll(m & ((1ull << lane) - 1ull));
    int count = __popcll(m);
    int base = 0;
    if (lane == 0) base = atomicAdd(&lbase, count);
    base = __shfl(base, 0, 64);
    if (ok) be[base + rank] = p;
  }
  __syncthreads();
  if (threadIdx.x == 0) cnt[e] = lbase;
}

// ---------------- grouped GEMM: 64x128 tile, dbuf LDS, DEPTH-2 register prefetch -----
// Per step k: ds_write tile k+1 (from regset k&1) -> reload that regset with tile k+3
// (2 full steps of load latency tolerance) -> MFMA tile k -> lgkm-only barrier (global
// loads stay in flight). LDS unpadded 64B rows + XOR swizzle (R6-measured 0 conflicts).
// hb is stored in BUCKET ORDER: row = ebase[e]+pos (ebase = prefix of cnt, computed
// in-kernel). GEMM2's A-read is therefore fully sequential (no gather, no fallback).
// FIRST: A = xb gathered by token; hb[ebase+pos][n] = gelu(A@W1t^T + b1)
// !FIRST: A = hb[ebase+i0+r] sequential; opb[pair][n] = bf16(pw*(A@W2t^T + b2))
template<int KDIM, int NDIM, bool FIRST>
__global__ __launch_bounds__(256) void moe_gemm(
    const unsigned short* __restrict__ A,
    const unsigned short* __restrict__ Bm,    // [E][NDIM][KDIM] bf16 (pre-transposed)
    const float* __restrict__ bias,           // [E][NDIM]
    const int* __restrict__ cnt,
    const int* __restrict__ bucket,
    const float* __restrict__ pw,
    unsigned short* __restrict__ hb,          // FIRST: output (bucket-order rows)
    unsigned short* __restrict__ opb)         // !FIRST: output (pair rows)
{
  int e  = blockIdx.z;
  int n0 = blockIdx.x * 128;
  int i0 = blockIdx.y * 64;
  int ce = cnt[e];
  if (i0 >= ce) return;
  int ebase = 0;
  for (int j=0;j<e;j++) ebase += cnt[j];      // 16 scalar L2 loads, once per block
  constexpr int NS = KDIM / 32;               // K-steps (16 or 32)

  __shared__ unsigned short As[2*64*32];      //  8 KB (two buffers)
  __shared__ unsigned short Bs[2*128*32];     // 16 KB

  int tid = threadIdx.x;
  int lane = tid & 63, wid = tid >> 6;
  int wm = (wid>>1)*32, wn = (wid&1)*64;

  // staging: thread -> row lr0 (0..63), logical col8 c (0..3); swizzled LDS col
  int lr0 = tid >> 2;
  int c   = tid & 3;
  int sc  = (c ^ ((lr0 >> 1) & 3)) * 8;
  int wA  = lr0*32 + sc;
  const int* buck = bucket + e*T_TOK;
  int posA  = i0 + lr0;
  int arow;
  if (FIRST){
    int pair = (posA < ce) ? buck[posA] : buck[i0];
    arow = pair >> 1;
  } else {
    arow = ebase + posA;                       // sequential bucket-order row
    if (arow > NPAIR-1) arow = NPAIR-1;        // tail guard (stores guarded anyway)
  }
  const unsigned short* Ag = A + (size_t)arow*KDIM + c*8;
  const unsigned short* Bg = Bm + (size_t)e*NDIM*KDIM + (size_t)(n0 + lr0)*KDIM + c*8;

  f32x4 acc[2][4];
  #pragma unroll
  for (int a=0;a<2;a++)
    #pragma unroll
    for (int b=0;b<4;b++)
      #pragma unroll
      for (int j=0;j<4;j++) acc[a][b][j] = 0.f;

  // frag-read addressing (swizzled)
  int fr = lane & 15, fb = lane >> 4;
  int pf8 = (fb ^ ((fr >> 1) & 3)) * 8;

  // ---- prologue: tile0 -> buf0; regset0 = tile1, regset1 = tile2 ----
  {
    float4 a0 = *(const float4*)(Ag);
    float4 b0 = *(const float4*)(Bg);
    float4 b1 = *(const float4*)(Bg + (size_t)64*KDIM);
    *(float4*)(As + wA) = a0;
    *(float4*)(Bs + wA) = b0;
    *(float4*)(Bs + wA + 64*32) = b1;
  }
  float4 pa[2], pb0[2], pb1[2];
  #pragma unroll
  for (int s=0;s<2;s++){
    int kk = (s+1)*32;     // tile1, tile2
    bool ok = (s+1) < NS;
    if (ok){
      pa[s]  = *(const float4*)(Ag + kk);
      pb0[s] = *(const float4*)(Bg + kk);
      pb1[s] = *(const float4*)(Bg + (size_t)64*KDIM + kk);
    }
  }
  __syncthreads();   // one-time full drain (tile0 staged via LDS)

  #pragma unroll 2
  for (int k = 0; k < NS; k++){
    const int cur = k & 1, nxt = cur ^ 1, s = k & 1;
    // ds_write tile k+1 from regset s into buf nxt
    if (k + 1 < NS){
      *(float4*)(As + nxt*2048 + wA) = pa[s];
      *(float4*)(Bs + nxt*4096 + wA) = pb0[s];
      *(float4*)(Bs + nxt*4096 + wA + 64*32) = pb1[s];
    }
    // reload regset s with tile k+3 (consumed 2 steps from now)
    if (k + 3 < NS){
      int kk = (k+3)*32;
      pa[s]  = *(const float4*)(Ag + kk);
      pb0[s] = *(const float4*)(Bg + kk);
      pb1[s] = *(const float4*)(Bg + (size_t)64*KDIM + kk);
    }
    const unsigned short* Ac = As + cur*2048;
    const unsigned short* Bc = Bs + cur*4096;
    bf16x8 af[2], bfr[4];
    #pragma unroll
    for (int s2=0;s2<2;s2++) af[s2]  = *(const bf16x8*)(Ac + (wm + s2*16 + fr)*32 + pf8);
    #pragma unroll
    for (int u=0;u<4;u++)    bfr[u]  = *(const bf16x8*)(Bc + (wn + u*16 + fr)*32 + pf8);
    #pragma unroll
    for (int s2=0;s2<2;s2++)
      #pragma unroll
      for (int u=0;u<4;u++)
        acc[s2][u] = __builtin_amdgcn_mfma_f32_16x16x32_bf16(af[s2], bfr[u], acc[s2][u], 0,0,0);
    barrier_lds_only();
  }

  // epilogue: C/D layout col=lane&15, row=(lane>>4)*4+reg  [m89-verified]
  int fq = (lane>>4)*4;
  #pragma unroll
  for (int s=0;s<2;s++){
    #pragma unroll
    for (int i=0;i<4;i++){
      int row = wm + s*16 + fq + i;
      int pos = i0 + row;
      if (pos >= ce) continue;
      #pragma unroll
      for (int u=0;u<4;u++){
        int n = n0 + wn + u*16 + fr;
        float v = acc[s][u][i] + bias[e*NDIM + n];
        if (FIRST){
          float g = 0.5f*v*(1.f + erff(v*0.70710678118654752f));   // exact GELU
          hb[(size_t)(ebase + pos)*NDIM + n] = f2b(g);
        } else {
          int pair = buck[pos];
          opb[(size_t)pair*NDIM + n] = f2b(pw[pair]*v);    // plain store, no atomics
        }
      }
    }
  }
}

// ---------------- combine: out = x + opb[2t] + opb[2t+1] (coalesced) ----------------
__global__ __launch_bounds__(256) void combine_kernel(const float* __restrict__ x,
                                                      const unsigned short* __restrict__ opb,
                                                      float* __restrict__ out){
  int i = blockIdx.x*256 + threadIdx.x;
  int t  = i >> 7;
  int c4 = i & 127;
  float4 v = ((const float4*)x)[i];
  ushort4 a = ((const ushort4*)opb)[(size_t)(2*t)*128 + c4];
  ushort4 b = ((const ushort4*)opb)[(size_t)(2*t+1)*128 + c4];
  v.x += b2f(a.x) + b2f(b.x);
  v.y += b2f(a.y) + b2f(b.y);
  v.z += b2f(a.z) + b2f(b.z);
  v.w += b2f(a.w) + b2f(b.w);
  ((float4*)out)[i] = v;
}

// ---------------- launch ----------------
extern "C" void kernel_launch(void* const* d_in, const int* in_sizes, int n_in,
                              void* d_out, int out_size, void* d_ws, size_t ws_size,
                              hipStream_t stream)
{
  const float* x  = (const float*)d_in[0];
  const float* Wr = (const float*)d_in[1];
  const float* br = (const float*)d_in[2];
  const float* W1 = (const float*)d_in[3];
  const float* b1 = (const float*)d_in[4];
  const float* W2 = (const float*)d_in[5];
  const float* b2 = (const float*)d_in[6];
  float* out = (float*)d_out;
  char* ws = (char*)d_ws;

  // ws layout (bytes) — identical footprint to the passing R1-R8 layout
  int*            cnt    = (int*)(ws + 0);            // 64 B
  int*            bucket = (int*)(ws + 1024);         // 16*8192*4 = 524288
  float*          pw     = (float*)(ws + 525312);     // 16384*4   = 65536
  unsigned short* xb     = (unsigned short*)(ws + 590848);    // 8192*512*2  = 8388608
  unsigned short* w1t    = (unsigned short*)(ws + 8979456);   // 16*512*1024*2 = 16777216
  unsigned short* w2t    = (unsigned short*)(ws + 25756672);  // 16777216
  unsigned short* hb     = (unsigned short*)(ws + 42533888);  // 16384*1024*2 = 33554432
  // aliases (stream-ordered lifetimes):
  //  eid at hb head: router writes, bucket reads, dead before GEMM1 writes hb
  //  opb in w1t region: w1t dead after GEMM1; opb = GEMM2 out, read by combine
  int*            eid    = (int*)(ws + 42533888);     // 16384*4 = 65536
  unsigned short* opb    = w1t;                       // 16384*512*2 = 16777216 (exact fit)

  router_kernel<<<T_TOK/4, 256, 0, stream>>>(x, Wr, br, xb, eid, pw);
  bucket_kernel<<<NE, 1024, 0, stream>>>(eid, cnt, bucket);
  tconv_kernel<<<dim3(HID/32, IN_DIM/32, NE), 256, 0, stream>>>(W1, w1t, IN_DIM, HID);
  tconv_kernel<<<dim3(IN_DIM/32, HID/32, NE), 256, 0, stream>>>(W2, w2t, HID, IN_DIM);
  moe_gemm<IN_DIM, HID, true ><<<dim3(HID/128,    T_TOK/64, NE), 256, 0, stream>>>(
      xb, w1t, b1, cnt, bucket, pw, hb, opb);
  moe_gemm<HID, IN_DIM, false><<<dim3(IN_DIM/128, T_TOK/64, NE), 256, 0, stream>>>(
      hb, w2t, b2, cnt, bucket, pw, hb, opb);
  combine_kernel<<<(T_TOK*IN_DIM/4)/256, 256, 0, stream>>>(x, opb, out);
}

// Round 10
// 282.949 us; speedup vs baseline: 1.6430x; 1.6430x over previous
//
#include <hip/hip_runtime.h>
#include <hip/hip_bf16.h>
#include <math.h>

#define IN_DIM 512
#define HID    1024
#define NE     16
#define T_TOK  8192
#define NPAIR  (T_TOK*2)

typedef __attribute__((ext_vector_type(8))) short bf16x8;
typedef __attribute__((ext_vector_type(4))) float f32x4;

__device__ __forceinline__ unsigned short f2b(float f){
  unsigned u = __float_as_uint(f);
  u += 0x7FFF + ((u >> 16) & 1);           // round-to-nearest-even
  return (unsigned short)(u >> 16);
}
__device__ __forceinline__ float b2f(unsigned short u){
  return __uint_as_float(((unsigned)u) << 16);
}

// Barrier WITHOUT the vmcnt(0) drain __syncthreads() forces (AITER/m139 pattern).
__device__ __forceinline__ void barrier_lds_only(){
  asm volatile("s_waitcnt lgkmcnt(0)" ::: "memory");
  __builtin_amdgcn_s_barrier();
}

// ---------------- prep: batched transpose + convert: [B][M][N] f32 -> [B][N][M] bf16 ----
__global__ __launch_bounds__(256) void tconv_kernel(const float* __restrict__ in,
                                                    unsigned short* __restrict__ out,
                                                    int M, int N){
  __shared__ float tile[32][33];
  int e  = blockIdx.z;
  int m0 = blockIdx.y*32, n0 = blockIdx.x*32;
  const float* src = in + (size_t)e*M*N;
  unsigned short* dst = out + (size_t)e*M*N;
  int c = threadIdx.x & 31, r = threadIdx.x >> 5;
  #pragma unroll
  for (int i=0;i<4;i++)
    tile[r + i*8][c] = src[(size_t)(m0 + r + i*8)*N + n0 + c];
  __syncthreads();
  int tr  = threadIdx.x >> 3;
  int tc4 = (threadIdx.x & 7) * 4;
  ushort4 o;
  o.x = f2b(tile[tc4+0][tr]); o.y = f2b(tile[tc4+1][tr]);
  o.z = f2b(tile[tc4+2][tr]); o.w = f2b(tile[tc4+3][tr]);
  *(ushort4*)(&dst[(size_t)(n0 + tr)*M + m0 + tc4]) = o;
}

// ---------------- router: one wave per token; NO global atomics ----------------
__global__ __launch_bounds__(256) void router_kernel(
    const float* __restrict__ x, const float* __restrict__ Wr, const float* __restrict__ br,
    unsigned short* __restrict__ xb, int* __restrict__ eid, float* __restrict__ pw)
{
  int wid = threadIdx.x >> 6, lane = threadIdx.x & 63;
  int t = blockIdx.x*4 + wid;
  const float4* xr4 = (const float4*)(x + (size_t)t*IN_DIM);
  ushort4*      xb4 = (ushort4*)(xb + (size_t)t*IN_DIM);

  float acc[NE];
  #pragma unroll
  for (int i=0;i<NE;i++) acc[i]=0.f;

  #pragma unroll
  for (int j=0;j<2;j++){
    int f = j*64 + lane;
    float4 v = xr4[f];
    ushort4 o; o.x=f2b(v.x); o.y=f2b(v.y); o.z=f2b(v.z); o.w=f2b(v.w);
    xb4[f] = o;
    const float4* wr4 = (const float4*)(Wr + (size_t)(f*4)*NE);
    const float* vv = (const float*)&v;
    #pragma unroll
    for (int rr=0; rr<4; rr++){
      float xv = vv[rr];
      #pragma unroll
      for (int q=0;q<4;q++){
        float4 w = wr4[rr*4+q];
        acc[q*4+0] += xv*w.x; acc[q*4+1] += xv*w.y;
        acc[q*4+2] += xv*w.z; acc[q*4+3] += xv*w.w;
      }
    }
  }
  #pragma unroll
  for (int off=32; off>=1; off>>=1){
    #pragma unroll
    for (int i=0;i<NE;i++) acc[i] += __shfl_xor(acc[i], off, 64);
  }
  if (lane==0){
    #pragma unroll
    for (int i=0;i<NE;i++) acc[i] += br[i];
    int e0=0; float l0=acc[0];
    #pragma unroll
    for (int i=1;i<NE;i++) if (acc[i] > l0){ l0=acc[i]; e0=i; }
    int e1=-1; float l1=-3.0e38f;
    #pragma unroll
    for (int i=0;i<NE;i++) if (i!=e0 && acc[i] > l1){ l1=acc[i]; e1=i; }
    float w0 = 1.f/(1.f + __expf(l1 - l0));
    float w1 = 1.f - w0;
    pw[t*2+0] = w0; pw[t*2+1] = w1;
    eid[t*2+0] = e0; eid[t*2+1] = e1;
  }
}

// ---------------- bucket build: 16 blocks (one per expert), ballot-compact ----------
__global__ __launch_bounds__(1024) void bucket_kernel(const int* __restrict__ eid,
                                                      int* __restrict__ cnt,
                                                      int* __restrict__ bucket){
  int e = blockIdx.x;
  __shared__ int lbase;
  if (threadIdx.x == 0) lbase = 0;
  __syncthreads();
  int lane = threadIdx.x & 63, wid = threadIdx.x >> 6;
  int* be = bucket + e*T_TOK;
  for (int c = wid*64; c < NPAIR; c += 1024){
    int p = c + lane;
    bool ok = (eid[p] == e);
    unsigned long long m = __ballot(ok);
    int rank = __popcll(m & ((1ull << lane) - 1ull));
    int count = __popcll(m);
    int base = 0;
    if (lane == 0) base = atomicAdd(&lbase, count);
    base = __shfl(base, 0, 64);
    if (ok) be[base + rank] = p;
  }
  __syncthreads();
  if (threadIdx.x == 0) cnt[e] = lbase;
}

// ---------------- PERSISTENT grouped GEMM: 64x128 tile, R6 K-loop body ---------------
// Grid = fixed 1024 blocks; each grid-strides a flat live-tile index (no dead blocks,
// even CU load). Tile order i0-fastest: concurrent blocks share the same B region (L2).
// Mapping tile->(e,i0,n0) by register scan of cnt[] (NO arrays -> no scratch, cf. R9).
// hb rows are in BUCKET ORDER (ebase+pos): GEMM1 scatter-writes by epilogue, GEMM2's
// A-staging reads fully sequential rows (no gather).
// FIRST: A = xb gathered by token; hb[ebase+pos][n] = gelu(A@W1t^T + b1)
// !FIRST: A = hb sequential; opb[pair][n] = bf16(pw[pair]*(A@W2t^T + b2)) (no atomics)
template<int KDIM, int NDIM, bool FIRST>
__global__ __launch_bounds__(256) void moe_gemm(
    const unsigned short* __restrict__ A,
    const unsigned short* __restrict__ Bm,    // [E][NDIM][KDIM] bf16 (pre-transposed)
    const float* __restrict__ bias,           // [E][NDIM]
    const int* __restrict__ cnt,
    const int* __restrict__ bucket,
    const float* __restrict__ pw,
    unsigned short* __restrict__ hb,          // FIRST: out (bucket-order) / !FIRST: in
    unsigned short* __restrict__ opb)         // !FIRST: out (pair rows)
{
  constexpr int NS  = KDIM / 32;              // K-steps per tile
  constexpr int NBT = NDIM / 128;             // n-tiles per expert

  int ntiles = 0;
  #pragma unroll
  for (int j=0;j<NE;j++) ntiles += ((cnt[j]+63)>>6)*NBT;

  __shared__ unsigned short As[2*64*32];      //  8 KB (two buffers)
  __shared__ unsigned short Bs[2*128*32];     // 16 KB

  int tid = threadIdx.x;
  int lane = tid & 63, wid = tid >> 6;
  int wm = (wid>>1)*32, wn = (wid&1)*64;
  int lr0 = tid >> 2;
  int c   = tid & 3;
  int sc  = (c ^ ((lr0 >> 1) & 3)) * 8;       // XOR-swizzled LDS col (R6: 0 conflicts)
  int wA  = lr0*32 + sc;
  int fr = lane & 15, fb = lane >> 4;
  int pf8 = (fb ^ ((fr >> 1) & 3)) * 8;
  int fq = (lane>>4)*4;

  for (int t = blockIdx.x; t < ntiles; t += gridDim.x){
    // ---- tile -> (e, tloc, ebase, ce, itl) via register scan (no arrays) ----
    int e=0, tloc=0, ebase=0, ce=0, itl=1;
    {
      int cum=0, crow=0;
      #pragma unroll
      for (int j=0;j<NE;j++){
        int cj = cnt[j];
        int it = (cj+63)>>6;
        int tj = it * NBT;
        bool in = (t >= cum) & (t < cum+tj);
        if (in){ e=j; tloc=t-cum; ebase=crow; ce=cj; itl=it; }
        cum += tj; crow += cj;
      }
    }
    int i0 = (tloc % itl) * 64;               // i0-fastest ordering
    int n0 = (tloc / itl) * 128;

    const int* buck = bucket + e*T_TOK;
    int posA = i0 + lr0;
    int arow;
    if (FIRST){
      int pair = (posA < ce) ? buck[posA] : buck[i0];
      arow = pair >> 1;
    } else {
      arow = ebase + posA;                    // sequential bucket-order row
      if (arow > NPAIR-1) arow = NPAIR-1;     // tail guard (stores epilogue-guarded)
    }
    const unsigned short* Ag = A + (size_t)arow*KDIM + c*8;
    const unsigned short* Bg = Bm + (size_t)e*NDIM*KDIM + (size_t)(n0 + lr0)*KDIM + c*8;

    f32x4 acc[2][4];
    #pragma unroll
    for (int a=0;a<2;a++)
      #pragma unroll
      for (int b=0;b<4;b++)
        #pragma unroll
        for (int j=0;j<4;j++) acc[a][b][j] = 0.f;

    // ---- prologue: tile0 -> buf0; regs = tile1 ----
    float4 ar, br0, br1;
    ar  = *(const float4*)(Ag);
    br0 = *(const float4*)(Bg);
    br1 = *(const float4*)(Bg + (size_t)64*KDIM);
    *(float4*)(As + wA) = ar;
    *(float4*)(Bs + wA) = br0;
    *(float4*)(Bs + wA + 64*32) = br1;
    ar  = *(const float4*)(Ag + 32);
    br0 = *(const float4*)(Bg + 32);
    br1 = *(const float4*)(Bg + (size_t)64*KDIM + 32);
    barrier_lds_only();

    #pragma unroll 2
    for (int k = 0; k < NS; k++){
      const int cur = k & 1, nxt = cur ^ 1;
      float4 na, nb0, nb1;
      bool ld = (k + 2 < NS);
      if (ld){
        na  = *(const float4*)(Ag + (k+2)*32);
        nb0 = *(const float4*)(Bg + (k+2)*32);
        nb1 = *(const float4*)(Bg + (size_t)64*KDIM + (k+2)*32);
      }
      if (k + 1 < NS){
        *(float4*)(As + nxt*2048 + wA) = ar;
        *(float4*)(Bs + nxt*4096 + wA) = br0;
        *(float4*)(Bs + nxt*4096 + wA + 64*32) = br1;
      }
      if (ld){ ar = na; br0 = nb0; br1 = nb1; }

      const unsigned short* Ac = As + cur*2048;
      const unsigned short* Bc = Bs + cur*4096;
      bf16x8 af[2], bfr[4];
      #pragma unroll
      for (int s=0;s<2;s++) af[s]  = *(const bf16x8*)(Ac + (wm + s*16 + fr)*32 + pf8);
      #pragma unroll
      for (int u=0;u<4;u++) bfr[u] = *(const bf16x8*)(Bc + (wn + u*16 + fr)*32 + pf8);
      #pragma unroll
      for (int s=0;s<2;s++)
        #pragma unroll
        for (int u=0;u<4;u++)
          acc[s][u] = __builtin_amdgcn_mfma_f32_16x16x32_bf16(af[s], bfr[u], acc[s][u], 0,0,0);
      barrier_lds_only();   // after this, all waves' LDS ops done -> next tile may restage
    }

    // ---- epilogue: C/D layout col=lane&15, row=(lane>>4)*4+reg [m89-verified] ----
    #pragma unroll
    for (int s=0;s<2;s++){
      #pragma unroll
      for (int i=0;i<4;i++){
        int row = wm + s*16 + fq + i;
        int pos = i0 + row;
        if (pos >= ce) continue;
        #pragma unroll
        for (int u=0;u<4;u++){
          int n = n0 + wn + u*16 + fr;
          float v = acc[s][u][i] + bias[e*NDIM + n];
          if (FIRST){
            float g = 0.5f*v*(1.f + erff(v*0.70710678118654752f));   // exact GELU
            hb[(size_t)(ebase + pos)*NDIM + n] = f2b(g);
          } else {
            int pair = buck[pos];
            opb[(size_t)pair*NDIM + n] = f2b(pw[pair]*v);
          }
        }
      }
    }
  }
}

// ---------------- combine: out = x + opb[2t] + opb[2t+1] (coalesced) ----------------
__global__ __launch_bounds__(256) void combine_kernel(const float* __restrict__ x,
                                                      const unsigned short* __restrict__ opb,
                                                      float* __restrict__ out){
  int i = blockIdx.x*256 + threadIdx.x;
  int t  = i >> 7;
  int c4 = i & 127;
  float4 v = ((const float4*)x)[i];
  ushort4 a = ((const ushort4*)opb)[(size_t)(2*t)*128 + c4];
  ushort4 b = ((const ushort4*)opb)[(size_t)(2*t+1)*128 + c4];
  v.x += b2f(a.x) + b2f(b.x);
  v.y += b2f(a.y) + b2f(b.y);
  v.z += b2f(a.z) + b2f(b.z);
  v.w += b2f(a.w) + b2f(b.w);
  ((float4*)out)[i] = v;
}

// ---------------- launch ----------------
extern "C" void kernel_launch(void* const* d_in, const int* in_sizes, int n_in,
                              void* d_out, int out_size, void* d_ws, size_t ws_size,
                              hipStream_t stream)
{
  const float* x  = (const float*)d_in[0];
  const float* Wr = (const float*)d_in[1];
  const float* br = (const float*)d_in[2];
  const float* W1 = (const float*)d_in[3];
  const float* b1 = (const float*)d_in[4];
  const float* W2 = (const float*)d_in[5];
  const float* b2 = (const float*)d_in[6];
  float* out = (float*)d_out;
  char* ws = (char*)d_ws;

  // ws layout (bytes) — identical footprint to the passing R1-R9 layout
  int*            cnt    = (int*)(ws + 0);            // 64 B
  int*            bucket = (int*)(ws + 1024);         // 16*8192*4 = 524288
  float*          pw     = (float*)(ws + 525312);     // 16384*4   = 65536
  unsigned short* xb     = (unsigned short*)(ws + 590848);    // 8192*512*2  = 8388608
  unsigned short* w1t    = (unsigned short*)(ws + 8979456);   // 16*512*1024*2 = 16777216
  unsigned short* w2t    = (unsigned short*)(ws + 25756672);  // 16777216
  unsigned short* hb     = (unsigned short*)(ws + 42533888);  // 16384*1024*2 = 33554432
  // aliases (stream-ordered lifetimes):
  //  eid at hb head: router writes, bucket reads, dead before GEMM1 writes hb
  //  opb in w1t region: w1t dead after GEMM1; opb = GEMM2 out, read by combine
  int*            eid    = (int*)(ws + 42533888);     // 16384*4 = 65536
  unsigned short* opb    = w1t;                       // 16384*512*2 = 16777216 (exact fit)

  router_kernel<<<T_TOK/4, 256, 0, stream>>>(x, Wr, br, xb, eid, pw);
  bucket_kernel<<<NE, 1024, 0, stream>>>(eid, cnt, bucket);
  tconv_kernel<<<dim3(HID/32, IN_DIM/32, NE), 256, 0, stream>>>(W1, w1t, IN_DIM, HID);
  tconv_kernel<<<dim3(IN_DIM/32, HID/32, NE), 256, 0, stream>>>(W2, w2t, HID, IN_DIM);
  moe_gemm<IN_DIM, HID, true ><<<1024, 256, 0, stream>>>(
      xb, w1t, b1, cnt, bucket, pw, hb, opb);
  moe_gemm<HID, IN_DIM, false><<<1024, 256, 0, stream>>>(
      hb, w2t, b2, cnt, bucket, pw, hb, opb);
  combine_kernel<<<(T_TOK*IN_DIM/4)/256, 256, 0, stream>>>(x, opb, out);
}